// Round 6
// baseline (929.106 us; speedup 1.0000x reference)
//
#include <hip/hip_runtime.h>
#include <cmath>

#define NEG -1e9f
constexpr int B = 8, N = 512, M = 512, D = 512;
constexpr size_t NM = (size_t)N * M;   // 262144

constexpr int CH = 16;          // chunk = barrier interval = wave skew
constexpr int NCH = 67;         // 67*16 = 1072 >= makespan 1023 + 3*16 + 1
// Forward: wave w (of 4) owns rows [128w,128w+127], active chunks [9w, 9w+39].
// Backward mirrored: active chunks [27-9w, 66-9w].

__device__ __forceinline__ int diag_off(int kd) {
    return (kd <= 511) ? ((kd * (kd + 1)) >> 1)
                       : ((int)NM - (((1023 - kd) * (1024 - kd)) >> 1));
}

// ---------------------------------------------------------------------------
// GEMM + activation: which=0 -> theta = softplus(zx . zy^T)
//                    which=1 -> A     = log_sigmoid(gx . gy^T)
// ---------------------------------------------------------------------------
__global__ __launch_bounds__(256)
void gemm_act_kernel(const float* __restrict__ zx, const float* __restrict__ zy,
                     const float* __restrict__ gx, const float* __restrict__ gy,
                     float* __restrict__ out_theta, float* __restrict__ out_A)
{
    const int bz = blockIdx.z;
    const int b = bz >> 1, which = bz & 1;
    const float* X = (which ? gx : zx) + (size_t)b * N * D;
    const float* Y = (which ? gy : zy) + (size_t)b * M * D;
    float* C = (which ? out_A : out_theta) + (size_t)b * NM;

    __shared__ float Xs[16][68];
    __shared__ float Ys[16][68];

    const int tx = threadIdx.x, ty = threadIdx.y;
    const int t = ty * 16 + tx;
    const int lrow = t >> 2;
    const int lk4 = (t & 3) * 4;
    const int row0 = blockIdx.y * 64, col0 = blockIdx.x * 64;

    float acc[4][4] = {};

    for (int k0 = 0; k0 < D; k0 += 16) {
        const float4 xv = *(const float4*)&X[(row0 + lrow) * D + k0 + lk4];
        const float4 yv = *(const float4*)&Y[(col0 + lrow) * D + k0 + lk4];
        Xs[lk4 + 0][lrow] = xv.x; Xs[lk4 + 1][lrow] = xv.y;
        Xs[lk4 + 2][lrow] = xv.z; Xs[lk4 + 3][lrow] = xv.w;
        Ys[lk4 + 0][lrow] = yv.x; Ys[lk4 + 1][lrow] = yv.y;
        Ys[lk4 + 2][lrow] = yv.z; Ys[lk4 + 3][lrow] = yv.w;
        __syncthreads();
#pragma unroll
        for (int kk = 0; kk < 16; kk++) {
            const float4 a = *(const float4*)&Xs[kk][ty * 4];
            const float4 bb = *(const float4*)&Ys[kk][tx * 4];
            acc[0][0] += a.x * bb.x; acc[0][1] += a.x * bb.y; acc[0][2] += a.x * bb.z; acc[0][3] += a.x * bb.w;
            acc[1][0] += a.y * bb.x; acc[1][1] += a.y * bb.y; acc[1][2] += a.y * bb.z; acc[1][3] += a.y * bb.w;
            acc[2][0] += a.z * bb.x; acc[2][1] += a.z * bb.y; acc[2][2] += a.z * bb.z; acc[2][3] += a.z * bb.w;
            acc[3][0] += a.w * bb.x; acc[3][1] += a.w * bb.y; acc[3][2] += a.w * bb.z; acc[3][3] += a.w * bb.w;
        }
        __syncthreads();
    }

#pragma unroll
    for (int r = 0; r < 4; r++) {
        float4 o;
        float* op = &o.x;
#pragma unroll
        for (int c = 0; c < 4; c++) {
            const float x = acc[r][c];
            const float l = log1pf(expf(-fabsf(x)));
            op[c] = which ? (fminf(x, 0.0f) - l)     // log_sigmoid
                          : (fmaxf(x, 0.0f) + l);   // softplus
        }
        *(float4*)&C[(size_t)(row0 + ty * 4 + r) * M + col0 + tx * 4] = o;
    }
}

// ---------------------------------------------------------------------------
// Row-major theta,A -> compact-diag interleaved float2 {theta, A}.
// ---------------------------------------------------------------------------
__global__ __launch_bounds__(256)
void reorder_in_kernel(const float* __restrict__ theta, const float* __restrict__ A,
                       float2* __restrict__ TAD)
{
    __shared__ float T[64][67];
    __shared__ float Ag[64][67];
    const int b = blockIdx.z;
    const float* ts = theta + (size_t)b * NM;
    const float* as = A + (size_t)b * NM;
    float2* dst = TAD + (size_t)b * NM;
    const int r0 = blockIdx.y * 64, c0 = blockIdx.x * 64;
    const int t = threadIdx.x, lane = t & 63, wv = t >> 6;

#pragma unroll
    for (int e = 0; e < 16; e++) {
        const int r = wv * 16 + e;
        T[r][lane]  = ts[(size_t)(r0 + r) * M + c0 + lane];
        Ag[r][lane] = as[(size_t)(r0 + r) * M + c0 + lane];
    }
    __syncthreads();
    for (int dd = wv; dd < 127; dd += 4) {
        const int kd = r0 + c0 + dd;
        const int rlo = max(0, dd - 63);
        const int L = min(63, dd) - rlo + 1;
        if (lane < L) {
            const int rloc = rlo + lane;
            const int gr = r0 + rloc;
            dst[diag_off(kd) + gr - max(0, kd - 511)] =
                make_float2(T[rloc][dd - rloc], Ag[rloc][dd - rloc]);
        }
    }
}

// ---------------------------------------------------------------------------
// Compact-diag E -> row-major aln.
// ---------------------------------------------------------------------------
__global__ __launch_bounds__(256)
void reorder_out_kernel(const float* __restrict__ ED, float* __restrict__ aln)
{
    __shared__ float T[64][67];
    const int b = blockIdx.z;
    const float* src = ED + (size_t)b * NM;
    float* dst = aln + (size_t)b * NM;
    const int r0 = blockIdx.y * 64, c0 = blockIdx.x * 64;
    const int t = threadIdx.x, lane = t & 63, wv = t >> 6;

    for (int dd = wv; dd < 127; dd += 4) {
        const int kd = r0 + c0 + dd;
        const int rlo = max(0, dd - 63);
        const int L = min(63, dd) - rlo + 1;
        if (lane < L) {
            const int rloc = rlo + lane;
            const int gr = r0 + rloc;
            T[rloc][dd - rloc] = src[diag_off(kd) + gr - max(0, kd - 511)];
        }
    }
    __syncthreads();
#pragma unroll
    for (int e = 0; e < 16; e++) {
        const int r = wv * 16 + e;
        dst[(size_t)(r0 + r) * M + c0 + lane] = T[r][lane];
    }
}

// ---------------------------------------------------------------------------
// Forward soft-NW: 2 cells/thread (rows ra=2t, rb=2t+1), 256 threads, 4 waves,
// skew=16. One shfl/step serves both cells: cell a's up/diag come from lane-1's
// row rb register; cell b's up/diag come from own row ra register (delayed).
// ---------------------------------------------------------------------------
__global__ __launch_bounds__(256)
void nw_forward_kernel(const float2* __restrict__ TAD, float2* __restrict__ pD)
{
    __shared__ float ring[4][64];
    const int b = blockIdx.x;
    const int tid = threadIdx.x;
    const int w = __builtin_amdgcn_readfirstlane(tid >> 6);
    const int lane = tid & 63;
    const int t2 = tid * 2;                   // row a
    const float2* tab = TAD + (size_t)b * NM;
    float2* pb = pD + (size_t)b * NM;

    for (int x = tid; x < 4 * 64; x += 256) ((float*)ring)[x] = NEG;
    __syncthreads();

    const int ca = 9 * w, cz = 9 * w + 39;

    float2 cA[CH], cB[CH], nA[CH], nB[CH];
    if (w == 0) {
#pragma unroll
        for (int s = 0; s < CH; s++) {        // chunk 0: kd = s, in range
            const int S = diag_off(s) - max(0, s - 511);
            cA[s] = tab[S + t2];
            cB[s] = tab[S + t2 + 1];
        }
    }

    float va = NEG, vb = NEG;       // V[ra,.], V[rb,.] (latest valid step)
    float sha_d = NEG, va_d = NEG;  // shfl delayed 1 step; va delayed 1 step (pre-update)

    for (int c = 0; c < NCH; c++) {
        const bool pf = (c + 1 >= ca) && (c + 1 <= cz);
        if (pf) {
            const int kb1 = 16 * (c + 1 - w);
#pragma unroll
            for (int s = 0; s < CH; s++) {
                const int kc = min(max(kb1 + s, 0), 1022);
                const int S = diag_off(kc) - max(0, kc - 511);
                nA[s] = tab[S + t2];
                nB[s] = tab[S + t2 + 1];
            }
        }
        if (c >= ca && c <= cz) {
            const int kb = 16 * (c - w);
            float rg[CH];
#pragma unroll
            for (int s = 0; s < CH; s++)
                rg[s] = (w > 0) ? ring[w - 1][(kb + s - 1) & 63] : NEG;
#pragma unroll
            for (int s = 0; s < CH; s++) {
                const int kd = kb + s;
                const int ja = kd - t2;                 // col of cell a; jb = ja-1
                float sha = __shfl_up(vb, 1);           // V[ra-1, ja] (lane-1 row rb)
                if (lane == 0) sha = rg[s];
                const float upb = va;                   // V[ra, jb] (pre-update)
                const float dga = (ja == 0) ? ((tid == 0) ? 0.0f : NEG) : sha_d;
                const float dgb = (ja == 1) ? NEG : va_d;
                const int S = diag_off(kd) - max(0, kd - 511);
                const int f = S + t2;
                float vna = va, vnb = vb;
                if (ja >= 0 && ja < M) {                // cell a
                    const float th = cA[s].x, aa = cA[s].y;
                    const float x0 = aa + sha, x2 = aa + va;
                    const float m = fmaxf(fmaxf(x0, dga), x2);
                    const float e0 = __expf(x0 - m);
                    const float e1 = __expf(dga - m);
                    const float e2 = __expf(x2 - m);
                    const float sum = e0 + e1 + e2;
                    const float inv = __builtin_amdgcn_rcpf(sum);
                    pb[f] = make_float2(e0 * inv, e2 * inv);
                    vna = th + m + __logf(sum);
                }
                if (ja >= 1 && ja <= M) {               // cell b (jb in [0,M))
                    const float th = cB[s].x, ab = cB[s].y;
                    const float x0 = ab + upb, x2 = ab + vb;
                    const float m = fmaxf(fmaxf(x0, dgb), x2);
                    const float e0 = __expf(x0 - m);
                    const float e1 = __expf(dgb - m);
                    const float e2 = __expf(x2 - m);
                    const float sum = e0 + e1 + e2;
                    const float inv = __builtin_amdgcn_rcpf(sum);
                    pb[f + 1] = make_float2(e0 * inv, e2 * inv);
                    vnb = th + m + __logf(sum);
                }
                sha_d = sha; va_d = upb;
                va = vna; vb = vnb;
                if (lane == 63) ring[w][kd & 63] = vnb; // row 128w+127 publish
            }
        }
        if (pf) {
#pragma unroll
            for (int s = 0; s < CH; s++) { cA[s] = nA[s]; cB[s] = nB[s]; }
        }
        __syncthreads();
    }
}

// ---------------------------------------------------------------------------
// Backward adjoint, q-product form, 2 cells/thread, skew=16 mirrored (wave 3
// leads). e = su + sd + ql1; q_* = p_* e; p_dg = 1 - p_up - p_lf.
//  cell b neighbors (row rb+1 = lane+1's ra): 2 shfl_down (su @kd+1; qd @kd+1
//  delayed 1 step -> @kd+2). cell a neighbors (row ra+1 = own rb): registers.
// ---------------------------------------------------------------------------
__global__ __launch_bounds__(256)
void nw_backward_kernel(const float2* __restrict__ pD, float* __restrict__ ED)
{
    __shared__ float ring_u[4][64];
    __shared__ float ring_d[4][64];
    const int b = blockIdx.x;
    const int tid = threadIdx.x;
    const int w = __builtin_amdgcn_readfirstlane(tid >> 6);
    const int lane = tid & 63;
    const int t2 = tid * 2;
    const float2* pb = pD + (size_t)b * NM;
    float* eb = ED + (size_t)b * NM;

    for (int x = tid; x < 4 * 64; x += 256) {
        ((float*)ring_u)[x] = 0.0f;
        ((float*)ring_d)[x] = 0.0f;
    }
    __syncthreads();

    const int ca = 27 - 9 * w, cz = 66 - 9 * w;

    float2 cA[CH], cB[CH], nA[CH], nB[CH];
    if (w == 3) {
#pragma unroll
        for (int s = 0; s < CH; s++) {        // chunk 0: kd = 1022 - s
            const int kc = 1022 - s;
            const int S = diag_off(kc) - max(0, kc - 511);
            cA[s] = pb[S + t2];
            cB[s] = pb[S + t2 + 1];
        }
    }

    float qu_a1 = 0.0f, qd_a1 = 0.0f, ql_a1 = 0.0f;
    float qu_b1 = 0.0f, qd_b1 = 0.0f, qd_b2 = 0.0f, ql_b1 = 0.0f;
    float sx_d = 0.0f;

    for (int c = 0; c < NCH; c++) {
        const bool pf = (c + 1 >= ca) && (c + 1 <= cz);
        if (pf) {
            const int kb1 = 1070 - 16 * (c + 1) - 16 * w;
#pragma unroll
            for (int s = 0; s < CH; s++) {
                const int kc = min(max(kb1 - s, 0), 1022);
                const int S = diag_off(kc) - max(0, kc - 511);
                nA[s] = pb[S + t2];
                nB[s] = pb[S + t2 + 1];
            }
        }
        if (c >= ca && c <= cz) {
            const int kb = 1070 - 16 * c - 16 * w;
            float rgu[CH], rgd[CH];
#pragma unroll
            for (int s = 0; s < CH; s++) {
                rgu[s] = (w < 3) ? ring_u[w + 1][(kb - s + 1) & 63] : 0.0f;
                rgd[s] = (w < 3) ? ring_d[w + 1][(kb - s + 2) & 63] : 0.0f;
            }
#pragma unroll
            for (int s = 0; s < CH; s++) {
                const int kd = kb - s;
                const int ja = kd - t2;                 // col of cell a; jb = ja-1
                const int jb = ja - 1;
                float su_b = __shfl_down(qu_a1, 1);     // lane+1 q_up(ra') @ kd+1
                float sx   = __shfl_down(qd_a1, 1);     // lane+1 q_dg(ra') @ kd+1
                float sd_b = sx_d;                      // lane+1 q_dg(ra') @ kd+2
                if (lane == 63) { su_b = rgu[s]; sd_b = rgd[s]; }
                const float su_a = qu_b1;               // own rb @ kd+1
                const float sd_a = qd_b2;               // own rb @ kd+2
                const int S = diag_off(kd) - max(0, kd - 511);
                const int f = S + t2;
                if (ja >= 0 && ja < M) {                // cell a
                    const float e = su_a + sd_a + ql_a1;
                    const float pu = cA[s].x, pl = cA[s].y;
                    const float pd = 1.0f - pu - pl;
                    eb[f] = e;
                    qu_a1 = pu * e; qd_a1 = pd * e; ql_a1 = pl * e;
                    if (lane == 0) {
                        ring_u[w][kd & 63] = qu_a1;
                        ring_d[w][kd & 63] = qd_a1;
                    }
                }
                if (jb >= 0 && jb < M) {                // cell b
                    float e = su_b + sd_b + ql_b1;
                    if (tid == 255 && jb == M - 1) e = 1.0f;   // seed E[N,M]
                    const float pu = cB[s].x, pl = cB[s].y;
                    const float pd = 1.0f - pu - pl;
                    eb[f + 1] = e;
                    qd_b2 = qd_b1; qd_b1 = pd * e; qu_b1 = pu * e; ql_b1 = pl * e;
                }
                sx_d = sx;
            }
        }
        if (pf) {
#pragma unroll
            for (int s = 0; s < CH; s++) { cA[s] = nA[s]; cB[s] = nB[s]; }
        }
        __syncthreads();
    }
}

// ---------------------------------------------------------------------------
extern "C" void kernel_launch(void* const* d_in, const int* in_sizes, int n_in,
                              void* d_out, int out_size, void* d_ws, size_t ws_size,
                              hipStream_t stream) {
    const float* zx = (const float*)d_in[0];
    const float* zy = (const float*)d_in[1];
    const float* gx = (const float*)d_in[2];
    const float* gy = (const float*)d_in[3];

    float* aln   = (float*)d_out;               // output 0: [B,N,M]
    float* theta = aln + B * NM;                // output 1
    float* Amat  = theta + B * NM;              // output 2

    float2* TAD = (float2*)d_ws;                // {theta,A} diag-interleaved, 16 MB
    float2* pD  = TAD + B * NM;                 // {p_up,p_lf} diag-interleaved, 16 MB
    float*  ED  = (float*)d_ws;                 // overlays TAD (dead after forward)

    gemm_act_kernel<<<dim3(8, 8, B * 2), dim3(16, 16), 0, stream>>>(zx, zy, gx, gy, theta, Amat);
    reorder_in_kernel<<<dim3(8, 8, B), 256, 0, stream>>>(theta, Amat, TAD);
    nw_forward_kernel<<<B, 256, 0, stream>>>(TAD, pD);
    nw_backward_kernel<<<B, 256, 0, stream>>>(pD, ED);
    reorder_out_kernel<<<dim3(8, 8, B), 256, 0, stream>>>(ED, aln);
}

// Round 7
// 795.040 us; speedup vs baseline: 1.1686x; 1.1686x over previous
//
#include <hip/hip_runtime.h>
#include <cmath>

#define NEG -1e9f
constexpr int B = 8, N = 512, M = 512, D = 512;
constexpr size_t NM = (size_t)N * M;   // 262144

constexpr int CH = 16;          // chunk = barrier interval = wave skew
constexpr int NCH = 71;         // 71*16 = 1136 >= 1023 + 7*16 + 1 makespan
// Active chunk windows: forward wave w: [5w, 5w+35]; backward: [35-5w, 70-5w].

// DPP full-wave shifts (register-file, ~4 cyc; replaces ds_bpermute ~100+ cyc).
// wave_shr:1 = 0x138: lane n reads lane n-1 (== __shfl_up(v,1); lane0 keeps old=v).
// wave_shl:1 = 0x130: lane n reads lane n+1 (== __shfl_down(v,1); lane63 keeps old=v).
__device__ __forceinline__ float dpp_shr1(float v) {
    return __int_as_float(__builtin_amdgcn_update_dpp(
        __float_as_int(v), __float_as_int(v), 0x138, 0xf, 0xf, false));
}
__device__ __forceinline__ float dpp_shl1(float v) {
    return __int_as_float(__builtin_amdgcn_update_dpp(
        __float_as_int(v), __float_as_int(v), 0x130, 0xf, 0xf, false));
}

// Compact diagonal layout: cell (r,c) 0-based -> diag_off(kd) + r - max(0,kd-511)
__device__ __forceinline__ int diag_off(int kd) {
    return (kd <= 511) ? ((kd * (kd + 1)) >> 1)
                       : ((int)NM - (((1023 - kd) * (1024 - kd)) >> 1));
}
__device__ __forceinline__ int diag_flat_clamped(int kd, int r) {
    const int k = min(max(kd, 0), 1022);
    const int f = diag_off(k) + r - max(0, k - 511);
    return min(max(f, 0), (int)NM - 1);
}

// ---------------------------------------------------------------------------
// GEMM + activation: which=0 -> theta = softplus(zx . zy^T)
//                    which=1 -> A     = log_sigmoid(gx . gy^T)
// ---------------------------------------------------------------------------
__global__ __launch_bounds__(256)
void gemm_act_kernel(const float* __restrict__ zx, const float* __restrict__ zy,
                     const float* __restrict__ gx, const float* __restrict__ gy,
                     float* __restrict__ out_theta, float* __restrict__ out_A)
{
    const int bz = blockIdx.z;
    const int b = bz >> 1, which = bz & 1;
    const float* X = (which ? gx : zx) + (size_t)b * N * D;
    const float* Y = (which ? gy : zy) + (size_t)b * M * D;
    float* C = (which ? out_A : out_theta) + (size_t)b * NM;

    __shared__ float Xs[16][68];
    __shared__ float Ys[16][68];

    const int tx = threadIdx.x, ty = threadIdx.y;
    const int t = ty * 16 + tx;
    const int lrow = t >> 2;
    const int lk4 = (t & 3) * 4;
    const int row0 = blockIdx.y * 64, col0 = blockIdx.x * 64;

    float acc[4][4] = {};

    for (int k0 = 0; k0 < D; k0 += 16) {
        const float4 xv = *(const float4*)&X[(row0 + lrow) * D + k0 + lk4];
        const float4 yv = *(const float4*)&Y[(col0 + lrow) * D + k0 + lk4];
        Xs[lk4 + 0][lrow] = xv.x; Xs[lk4 + 1][lrow] = xv.y;
        Xs[lk4 + 2][lrow] = xv.z; Xs[lk4 + 3][lrow] = xv.w;
        Ys[lk4 + 0][lrow] = yv.x; Ys[lk4 + 1][lrow] = yv.y;
        Ys[lk4 + 2][lrow] = yv.z; Ys[lk4 + 3][lrow] = yv.w;
        __syncthreads();
#pragma unroll
        for (int kk = 0; kk < 16; kk++) {
            const float4 a = *(const float4*)&Xs[kk][ty * 4];
            const float4 bb = *(const float4*)&Ys[kk][tx * 4];
            acc[0][0] += a.x * bb.x; acc[0][1] += a.x * bb.y; acc[0][2] += a.x * bb.z; acc[0][3] += a.x * bb.w;
            acc[1][0] += a.y * bb.x; acc[1][1] += a.y * bb.y; acc[1][2] += a.y * bb.z; acc[1][3] += a.y * bb.w;
            acc[2][0] += a.z * bb.x; acc[2][1] += a.z * bb.y; acc[2][2] += a.z * bb.z; acc[2][3] += a.z * bb.w;
            acc[3][0] += a.w * bb.x; acc[3][1] += a.w * bb.y; acc[3][2] += a.w * bb.z; acc[3][3] += a.w * bb.w;
        }
        __syncthreads();
    }

#pragma unroll
    for (int r = 0; r < 4; r++) {
        float4 o;
        float* op = &o.x;
#pragma unroll
        for (int c = 0; c < 4; c++) {
            const float x = acc[r][c];
            const float l = log1pf(expf(-fabsf(x)));
            op[c] = which ? (fminf(x, 0.0f) - l)     // log_sigmoid
                          : (fmaxf(x, 0.0f) + l);   // softplus
        }
        *(float4*)&C[(size_t)(row0 + ty * 4 + r) * M + col0 + tx * 4] = o;
    }
}

// ---------------------------------------------------------------------------
// Row-major theta,A -> compact-diag interleaved float2 {theta, A}.
// ---------------------------------------------------------------------------
__global__ __launch_bounds__(256)
void reorder_in_kernel(const float* __restrict__ theta, const float* __restrict__ A,
                       float2* __restrict__ TAD)
{
    __shared__ float T[64][67];    // stride 67 -> diag reads 2-way banks (free)
    __shared__ float Ag[64][67];
    const int b = blockIdx.z;
    const float* ts = theta + (size_t)b * NM;
    const float* as = A + (size_t)b * NM;
    float2* dst = TAD + (size_t)b * NM;
    const int r0 = blockIdx.y * 64, c0 = blockIdx.x * 64;
    const int t = threadIdx.x, lane = t & 63, wv = t >> 6;

#pragma unroll
    for (int e = 0; e < 16; e++) {
        const int r = wv * 16 + e;
        T[r][lane]  = ts[(size_t)(r0 + r) * M + c0 + lane];
        Ag[r][lane] = as[(size_t)(r0 + r) * M + c0 + lane];
    }
    __syncthreads();
    for (int dd = wv; dd < 127; dd += 4) {
        const int kd = r0 + c0 + dd;
        const int rlo = max(0, dd - 63);
        const int L = min(63, dd) - rlo + 1;
        if (lane < L) {
            const int rloc = rlo + lane;
            const int gr = r0 + rloc;
            dst[diag_off(kd) + gr - max(0, kd - 511)] =
                make_float2(T[rloc][dd - rloc], Ag[rloc][dd - rloc]);
        }
    }
}

// ---------------------------------------------------------------------------
// Compact-diag E -> row-major aln.
// ---------------------------------------------------------------------------
__global__ __launch_bounds__(256)
void reorder_out_kernel(const float* __restrict__ ED, float* __restrict__ aln)
{
    __shared__ float T[64][67];
    const int b = blockIdx.z;
    const float* src = ED + (size_t)b * NM;
    float* dst = aln + (size_t)b * NM;
    const int r0 = blockIdx.y * 64, c0 = blockIdx.x * 64;
    const int t = threadIdx.x, lane = t & 63, wv = t >> 6;

    for (int dd = wv; dd < 127; dd += 4) {
        const int kd = r0 + c0 + dd;
        const int rlo = max(0, dd - 63);
        const int L = min(63, dd) - rlo + 1;
        if (lane < L) {
            const int rloc = rlo + lane;
            const int gr = r0 + rloc;
            T[rloc][dd - rloc] = src[diag_off(kd) + gr - max(0, kd - 511)];
        }
    }
    __syncthreads();
#pragma unroll
    for (int e = 0; e < 16; e++) {
        const int r = wv * 16 + e;
        dst[(size_t)(r0 + r) * M + c0 + lane] = T[r][lane];
    }
}

// ---------------------------------------------------------------------------
// Forward soft-NW: skew=16 wave pipeline (8 waves, 1 row/lane), chunk-skipping,
// float2 staged loads, float2 p-store, DPP wave_shr1 for the row-shift.
// ---------------------------------------------------------------------------
__global__ __launch_bounds__(512)
void nw_forward_kernel(const float2* __restrict__ TAD, float2* __restrict__ pD)
{
    __shared__ float ring[8][64];
    const int b = blockIdx.x;
    const int tid = threadIdx.x;
    const int w = __builtin_amdgcn_readfirstlane(tid >> 6);
    const int lane = tid & 63;
    const float2* tab = TAD + (size_t)b * NM;
    float2* pb = pD + (size_t)b * NM;

    for (int x = tid; x < 8 * 64; x += 512) ((float*)ring)[x] = NEG;
    __syncthreads();

    const int ca = 5 * w, cb = 5 * w + 35;

    float2 cur[CH], nxt[CH];
    if (w == 0) {
#pragma unroll
        for (int s = 0; s < CH; s++)
            cur[s] = tab[diag_flat_clamped(s, tid)];
    }

    float vprev = NEG, sh1_d = NEG;

    for (int c = 0; c < NCH; c++) {
        const bool pf = (c + 1 >= ca) && (c + 1 <= cb);
        if (pf) {
            const int kb = 16 * (c + 1) - 16 * w;
#pragma unroll
            for (int s = 0; s < CH; s++)
                nxt[s] = tab[diag_flat_clamped(kb + s, tid)];
        }
        if (c >= ca && c <= cb) {
            const int kb = 16 * c - 16 * w;
            float rg[CH];
#pragma unroll
            for (int s = 0; s < CH; s++)
                rg[s] = (w > 0) ? ring[w - 1][(kb + s - 1) & 63] : NEG;
#pragma unroll
            for (int s = 0; s < CH; s++) {
                const int kd = kb + s;
                const int jj = kd - tid;
                float sh1 = dpp_shr1(vprev);           // V[i-1, j] (lane n-1)
                if (lane == 0) sh1 = rg[s];
                const float dg = (jj == 0) ? ((tid == 0) ? 0.0f : NEG) : sh1_d;
                sh1_d = sh1;
                if (jj >= 0 && jj < M) {
                    const float th = cur[s].x, a = cur[s].y;
                    const float x0 = a + sh1;          // up
                    const float x2 = a + vprev;        // left
                    const float m = fmaxf(fmaxf(x0, dg), x2);
                    const float e0 = __expf(x0 - m);
                    const float e1 = __expf(dg - m);
                    const float e2 = __expf(x2 - m);
                    const float sum = e0 + e1 + e2;
                    const float inv = __builtin_amdgcn_rcpf(sum);
                    const int f = diag_off(kd) + tid - max(0, kd - 511);
                    pb[f] = make_float2(e0 * inv, e2 * inv);   // {p_up, p_lf}
                    vprev = th + m + __logf(sum);
                    if (lane == 63) ring[w][kd & 63] = vprev;
                }
            }
        }
        if (pf) {
#pragma unroll
            for (int s = 0; s < CH; s++) cur[s] = nxt[s];
        }
        __syncthreads();
    }
}

// ---------------------------------------------------------------------------
// Backward adjoint, q-product form, skew=16 mirrored (wave 7 leads), DPP
// wave_shl1 for the row-shift:
//  kd = 1134 - t - 16w (descending), jj = kd - tid.
//  e = su + sd + ql1; q_* = p_* e; p_dg = 1 - p_up - p_lf.
// ---------------------------------------------------------------------------
__global__ __launch_bounds__(512)
void nw_backward_kernel(const float2* __restrict__ pD, float* __restrict__ ED)
{
    __shared__ float ring_u[8][64];
    __shared__ float ring_d[8][64];
    const int b = blockIdx.x;
    const int tid = threadIdx.x;
    const int w = __builtin_amdgcn_readfirstlane(tid >> 6);
    const int lane = tid & 63;
    const float2* pb = pD + (size_t)b * NM;
    float* eb = ED + (size_t)b * NM;

    for (int x = tid; x < 8 * 64; x += 512) {
        ((float*)ring_u)[x] = 0.0f;
        ((float*)ring_d)[x] = 0.0f;
    }
    __syncthreads();

    const int ca = 35 - 5 * w, cb = 70 - 5 * w;

    float2 cur[CH], nxt[CH];
    if (w == 7) {
#pragma unroll
        for (int s = 0; s < CH; s++)
            cur[s] = pb[diag_flat_clamped(1022 - s, tid)];
    }

    float qu1 = 0.0f, qd1 = 0.0f, qd2 = 0.0f, ql1 = 0.0f;

    for (int c = 0; c < NCH; c++) {
        const bool pf = (c + 1 >= ca) && (c + 1 <= cb);
        if (pf) {
            const int kb = 1134 - 16 * (c + 1) - 16 * w;
#pragma unroll
            for (int s = 0; s < CH; s++)
                nxt[s] = pb[diag_flat_clamped(kb - s, tid)];
        }
        if (c >= ca && c <= cb) {
            const int kb = 1134 - 16 * c - 16 * w;
            float rgu[CH], rgd[CH];
#pragma unroll
            for (int s = 0; s < CH; s++) {
                rgu[s] = (w < 7) ? ring_u[w + 1][(kb - s + 1) & 63] : 0.0f;
                rgd[s] = (w < 7) ? ring_d[w + 1][(kb - s + 2) & 63] : 0.0f;
            }
#pragma unroll
            for (int s = 0; s < CH; s++) {
                const int kd = kb - s;
                const int jj = kd - tid;
                float su = dpp_shl1(qu1);          // lane+1 q_up @ kd+1
                float sd = dpp_shl1(qd2);          // lane+1 q_dg @ kd+2
                if (lane == 63) { su = rgu[s]; sd = rgd[s]; }
                if (jj >= 0 && jj < M) {
                    float e = su + sd + ql1;
                    if (tid == N - 1 && jj == M - 1) e = 1.0f;   // seed E[N,M]
                    const float pu = cur[s].x, pl = cur[s].y;
                    const float pd = 1.0f - pu - pl;
                    const float qu = pu * e, qd = pd * e, ql = pl * e;
                    const int f = diag_off(kd) + tid - max(0, kd - 511);
                    eb[f] = e;
                    qd2 = qd1; qd1 = qd; qu1 = qu; ql1 = ql;
                    if (lane == 0) {
                        ring_u[w][kd & 63] = qu;
                        ring_d[w][kd & 63] = qd;
                    }
                }
            }
        }
        if (pf) {
#pragma unroll
            for (int s = 0; s < CH; s++) cur[s] = nxt[s];
        }
        __syncthreads();
    }
}

// ---------------------------------------------------------------------------
extern "C" void kernel_launch(void* const* d_in, const int* in_sizes, int n_in,
                              void* d_out, int out_size, void* d_ws, size_t ws_size,
                              hipStream_t stream) {
    const float* zx = (const float*)d_in[0];
    const float* zy = (const float*)d_in[1];
    const float* gx = (const float*)d_in[2];
    const float* gy = (const float*)d_in[3];

    float* aln   = (float*)d_out;               // output 0: [B,N,M]
    float* theta = aln + B * NM;                // output 1
    float* Amat  = theta + B * NM;              // output 2

    float2* TAD = (float2*)d_ws;                // {theta,A} diag-interleaved, 16 MB
    float2* pD  = TAD + B * NM;                 // {p_up,p_lf} diag-interleaved, 16 MB
    float*  ED  = (float*)d_ws;                 // overlays TAD (dead after forward)

    gemm_act_kernel<<<dim3(8, 8, B * 2), dim3(16, 16), 0, stream>>>(zx, zy, gx, gy, theta, Amat);
    reorder_in_kernel<<<dim3(8, 8, B), 256, 0, stream>>>(theta, Amat, TAD);
    nw_forward_kernel<<<B, 512, 0, stream>>>(TAD, pD);
    nw_backward_kernel<<<B, 512, 0, stream>>>(pD, ED);
    reorder_out_kernel<<<dim3(8, 8, B), 256, 0, stream>>>(ED, aln);
}

// Round 9
// 787.432 us; speedup vs baseline: 1.1799x; 1.0097x over previous
//
#include <hip/hip_runtime.h>
#include <cmath>

#define NEG -1e9f
constexpr int B = 8, N = 512, M = 512, D = 512;
constexpr size_t NM = (size_t)N * M;   // 262144

constexpr int CH = 16;          // chunk = barrier interval = wave skew
constexpr int NCH = 72;         // even; covers makespan 1023 + 7*16 + 1 (71 chunks)
// Active chunk windows: forward wave w: [5w, 5w+35]; backward: [35-5w, 70-5w].

// DPP full-wave shifts (register-file; replaces ds_bpermute).
__device__ __forceinline__ float dpp_shr1(float v) {
    return __int_as_float(__builtin_amdgcn_update_dpp(
        __float_as_int(v), __float_as_int(v), 0x138, 0xf, 0xf, false));
}
__device__ __forceinline__ float dpp_shl1(float v) {
    return __int_as_float(__builtin_amdgcn_update_dpp(
        __float_as_int(v), __float_as_int(v), 0x130, 0xf, 0xf, false));
}

// Compact diagonal layout: cell (r,c) 0-based -> diag_off(kd) + r - max(0,kd-511)
__device__ __forceinline__ int diag_off(int kd) {
    return (kd <= 511) ? ((kd * (kd + 1)) >> 1)
                       : ((int)NM - (((1023 - kd) * (1024 - kd)) >> 1));
}
__device__ __forceinline__ int diag_flat_clamped(int kd, int r) {
    const int k = min(max(kd, 0), 1022);
    const int f = diag_off(k) + r - max(0, k - 511);
    return min(max(f, 0), (int)NM - 1);
}

// ---------------------------------------------------------------------------
// GEMM + activation: which=0 -> theta = softplus(zx . zy^T)
//                    which=1 -> A     = log_sigmoid(gx . gy^T)
// ---------------------------------------------------------------------------
__global__ __launch_bounds__(256)
void gemm_act_kernel(const float* __restrict__ zx, const float* __restrict__ zy,
                     const float* __restrict__ gx, const float* __restrict__ gy,
                     float* __restrict__ out_theta, float* __restrict__ out_A)
{
    const int bz = blockIdx.z;
    const int b = bz >> 1, which = bz & 1;
    const float* X = (which ? gx : zx) + (size_t)b * N * D;
    const float* Y = (which ? gy : zy) + (size_t)b * M * D;
    float* C = (which ? out_A : out_theta) + (size_t)b * NM;

    __shared__ float Xs[16][68];
    __shared__ float Ys[16][68];

    const int tx = threadIdx.x, ty = threadIdx.y;
    const int t = ty * 16 + tx;
    const int lrow = t >> 2;
    const int lk4 = (t & 3) * 4;
    const int row0 = blockIdx.y * 64, col0 = blockIdx.x * 64;

    float acc[4][4] = {};

    for (int k0 = 0; k0 < D; k0 += 16) {
        const float4 xv = *(const float4*)&X[(row0 + lrow) * D + k0 + lk4];
        const float4 yv = *(const float4*)&Y[(col0 + lrow) * D + k0 + lk4];
        Xs[lk4 + 0][lrow] = xv.x; Xs[lk4 + 1][lrow] = xv.y;
        Xs[lk4 + 2][lrow] = xv.z; Xs[lk4 + 3][lrow] = xv.w;
        Ys[lk4 + 0][lrow] = yv.x; Ys[lk4 + 1][lrow] = yv.y;
        Ys[lk4 + 2][lrow] = yv.z; Ys[lk4 + 3][lrow] = yv.w;
        __syncthreads();
#pragma unroll
        for (int kk = 0; kk < 16; kk++) {
            const float4 a = *(const float4*)&Xs[kk][ty * 4];
            const float4 bb = *(const float4*)&Ys[kk][tx * 4];
            acc[0][0] += a.x * bb.x; acc[0][1] += a.x * bb.y; acc[0][2] += a.x * bb.z; acc[0][3] += a.x * bb.w;
            acc[1][0] += a.y * bb.x; acc[1][1] += a.y * bb.y; acc[1][2] += a.y * bb.z; acc[1][3] += a.y * bb.w;
            acc[2][0] += a.z * bb.x; acc[2][1] += a.z * bb.y; acc[2][2] += a.z * bb.z; acc[2][3] += a.z * bb.w;
            acc[3][0] += a.w * bb.x; acc[3][1] += a.w * bb.y; acc[3][2] += a.w * bb.z; acc[3][3] += a.w * bb.w;
        }
        __syncthreads();
    }

#pragma unroll
    for (int r = 0; r < 4; r++) {
        float4 o;
        float* op = &o.x;
#pragma unroll
        for (int c = 0; c < 4; c++) {
            const float x = acc[r][c];
            const float l = log1pf(expf(-fabsf(x)));
            op[c] = which ? (fminf(x, 0.0f) - l)     // log_sigmoid
                          : (fmaxf(x, 0.0f) + l);   // softplus
        }
        *(float4*)&C[(size_t)(row0 + ty * 4 + r) * M + col0 + tx * 4] = o;
    }
}

// ---------------------------------------------------------------------------
// Row-major theta,A -> compact-diag interleaved float2 {theta, A}.
// ---------------------------------------------------------------------------
__global__ __launch_bounds__(256)
void reorder_in_kernel(const float* __restrict__ theta, const float* __restrict__ A,
                       float2* __restrict__ TAD)
{
    __shared__ float T[64][67];
    __shared__ float Ag[64][67];
    const int b = blockIdx.z;
    const float* ts = theta + (size_t)b * NM;
    const float* as = A + (size_t)b * NM;
    float2* dst = TAD + (size_t)b * NM;
    const int r0 = blockIdx.y * 64, c0 = blockIdx.x * 64;
    const int t = threadIdx.x, lane = t & 63, wv = t >> 6;

#pragma unroll
    for (int e = 0; e < 16; e++) {
        const int r = wv * 16 + e;
        T[r][lane]  = ts[(size_t)(r0 + r) * M + c0 + lane];
        Ag[r][lane] = as[(size_t)(r0 + r) * M + c0 + lane];
    }
    __syncthreads();
    for (int dd = wv; dd < 127; dd += 4) {
        const int kd = r0 + c0 + dd;
        const int rlo = max(0, dd - 63);
        const int L = min(63, dd) - rlo + 1;
        if (lane < L) {
            const int rloc = rlo + lane;
            const int gr = r0 + rloc;
            dst[diag_off(kd) + gr - max(0, kd - 511)] =
                make_float2(T[rloc][dd - rloc], Ag[rloc][dd - rloc]);
        }
    }
}

// ---------------------------------------------------------------------------
// Compact-diag E -> row-major aln.
// ---------------------------------------------------------------------------
__global__ __launch_bounds__(256)
void reorder_out_kernel(const float* __restrict__ ED, float* __restrict__ aln)
{
    __shared__ float T[64][67];
    const int b = blockIdx.z;
    const float* src = ED + (size_t)b * NM;
    float* dst = aln + (size_t)b * NM;
    const int r0 = blockIdx.y * 64, c0 = blockIdx.x * 64;
    const int t = threadIdx.x, lane = t & 63, wv = t >> 6;

    for (int dd = wv; dd < 127; dd += 4) {
        const int kd = r0 + c0 + dd;
        const int rlo = max(0, dd - 63);
        const int L = min(63, dd) - rlo + 1;
        if (lane < L) {
            const int rloc = rlo + lane;
            const int gr = r0 + rloc;
            T[rloc][dd - rloc] = src[diag_off(kd) + gr - max(0, kd - 511)];
        }
    }
    __syncthreads();
#pragma unroll
    for (int e = 0; e < 16; e++) {
        const int r = wv * 16 + e;
        dst[(size_t)(r0 + r) * M + c0 + lane] = T[r][lane];
    }
}

// ---------------------------------------------------------------------------
// Forward soft-NW: skew=16 pipeline, DPP shift, TRUE register double-buffer:
// chunk loop unrolled x2 with bufA/bufB role swap (no copy, branchless defs).
// ---------------------------------------------------------------------------
#define FWD_CHUNK(c_, CUR, NXT)                                                \
    {                                                                          \
        const int c = (c_);                                                    \
        /* unconditional clamped prefetch of chunk c+1 into NXT */             \
        {                                                                      \
            const int kb1 = 16 * (c + 1) - 16 * w;                             \
            _Pragma("unroll")                                                  \
            for (int s = 0; s < CH; s++)                                       \
                NXT[s] = tab[diag_flat_clamped(kb1 + s, tid)];                 \
        }                                                                      \
        if (c >= ca && c <= cb) {                                              \
            const int kb = 16 * c - 16 * w;                                    \
            float rg[CH];                                                      \
            _Pragma("unroll")                                                  \
            for (int s = 0; s < CH; s++)                                       \
                rg[s] = (w > 0) ? ring[w - 1][(kb + s - 1) & 63] : NEG;        \
            _Pragma("unroll")                                                  \
            for (int s = 0; s < CH; s++) {                                     \
                const int kd = kb + s;                                         \
                const int jj = kd - tid;                                       \
                float sh1 = dpp_shr1(vprev);                                   \
                if (lane == 0) sh1 = rg[s];                                    \
                const float dg = (jj == 0) ? ((tid == 0) ? 0.0f : NEG) : sh1_d;\
                sh1_d = sh1;                                                   \
                if (jj >= 0 && jj < M) {                                       \
                    const float th = CUR[s].x, a = CUR[s].y;                   \
                    const float x0 = a + sh1;                                  \
                    const float x2 = a + vprev;                                \
                    const float m = fmaxf(fmaxf(x0, dg), x2);                  \
                    const float e0 = __expf(x0 - m);                           \
                    const float e1 = __expf(dg - m);                           \
                    const float e2 = __expf(x2 - m);                           \
                    const float sum = e0 + e1 + e2;                            \
                    const float inv = __builtin_amdgcn_rcpf(sum);              \
                    const int f = diag_off(kd) + tid - max(0, kd - 511);       \
                    pb[f] = make_float2(e0 * inv, e2 * inv);                   \
                    vprev = th + m + __logf(sum);                              \
                    if (lane == 63) ring[w][kd & 63] = vprev;                  \
                }                                                              \
            }                                                                  \
        }                                                                      \
        __syncthreads();                                                       \
    }

__global__ __launch_bounds__(512)
void nw_forward_kernel(const float2* __restrict__ TAD, float2* __restrict__ pD)
{
    __shared__ float ring[8][64];
    const int b = blockIdx.x;
    const int tid = threadIdx.x;
    const int w = __builtin_amdgcn_readfirstlane(tid >> 6);
    const int lane = tid & 63;
    const float2* tab = TAD + (size_t)b * NM;
    float2* pb = pD + (size_t)b * NM;

    for (int x = tid; x < 8 * 64; x += 512) ((float*)ring)[x] = NEG;
    __syncthreads();

    const int ca = 5 * w, cb = 5 * w + 35;

    float2 bufA[CH], bufB[CH];
#pragma unroll
    for (int s = 0; s < CH; s++)                   // chunk 0 data (only w==0 reads it)
        bufA[s] = tab[diag_flat_clamped(s - 16 * w, tid)];

    float vprev = NEG, sh1_d = NEG;

    for (int c2 = 0; c2 < NCH; c2 += 2) {
        FWD_CHUNK(c2,     bufA, bufB)
        FWD_CHUNK(c2 + 1, bufB, bufA)
    }
}

// ---------------------------------------------------------------------------
// Backward adjoint, q-product form, skew=16 mirrored (wave 7 leads), DPP,
// register ping-pong double-buffer.
// ---------------------------------------------------------------------------
#define BWD_CHUNK(c_, CUR, NXT)                                                \
    {                                                                          \
        const int c = (c_);                                                    \
        {                                                                      \
            const int kb1 = 1134 - 16 * (c + 1) - 16 * w;                      \
            _Pragma("unroll")                                                  \
            for (int s = 0; s < CH; s++)                                       \
                NXT[s] = pb[diag_flat_clamped(kb1 - s, tid)];                  \
        }                                                                      \
        if (c >= ca && c <= cb) {                                              \
            const int kb = 1134 - 16 * c - 16 * w;                             \
            float rgu[CH], rgd[CH];                                            \
            _Pragma("unroll")                                                  \
            for (int s = 0; s < CH; s++) {                                     \
                rgu[s] = (w < 7) ? ring_u[w + 1][(kb - s + 1) & 63] : 0.0f;    \
                rgd[s] = (w < 7) ? ring_d[w + 1][(kb - s + 2) & 63] : 0.0f;    \
            }                                                                  \
            _Pragma("unroll")                                                  \
            for (int s = 0; s < CH; s++) {                                     \
                const int kd = kb - s;                                         \
                const int jj = kd - tid;                                       \
                float su = dpp_shl1(qu1);                                      \
                float sd = dpp_shl1(qd2);                                      \
                if (lane == 63) { su = rgu[s]; sd = rgd[s]; }                  \
                if (jj >= 0 && jj < M) {                                       \
                    float e = su + sd + ql1;                                   \
                    if (tid == N - 1 && jj == M - 1) e = 1.0f;                 \
                    const float pu = CUR[s].x, pl = CUR[s].y;                  \
                    const float pd = 1.0f - pu - pl;                           \
                    const float qu = pu * e, qd = pd * e, ql = pl * e;         \
                    const int f = diag_off(kd) + tid - max(0, kd - 511);       \
                    eb[f] = e;                                                 \
                    qd2 = qd1; qd1 = qd; qu1 = qu; ql1 = ql;                   \
                    if (lane == 0) {                                           \
                        ring_u[w][kd & 63] = qu;                               \
                        ring_d[w][kd & 63] = qd;                               \
                    }                                                          \
                }                                                              \
            }                                                                  \
        }                                                                      \
        __syncthreads();                                                       \
    }

__global__ __launch_bounds__(512)
void nw_backward_kernel(const float2* __restrict__ pD, float* __restrict__ ED)
{
    __shared__ float ring_u[8][64];
    __shared__ float ring_d[8][64];
    const int b = blockIdx.x;
    const int tid = threadIdx.x;
    const int w = __builtin_amdgcn_readfirstlane(tid >> 6);
    const int lane = tid & 63;
    const float2* pb = pD + (size_t)b * NM;
    float* eb = ED + (size_t)b * NM;

    for (int x = tid; x < 8 * 64; x += 512) {
        ((float*)ring_u)[x] = 0.0f;
        ((float*)ring_d)[x] = 0.0f;
    }
    __syncthreads();

    const int ca = 35 - 5 * w, cb = 70 - 5 * w;

    float2 bufA[CH], bufB[CH];
#pragma unroll
    for (int s = 0; s < CH; s++)                   // chunk-0 data: kb(0)=1134-16w
        bufA[s] = pb[diag_flat_clamped(1134 - 16 * w - s, tid)];   // w=7 -> 1022-s

    float qu1 = 0.0f, qd1 = 0.0f, qd2 = 0.0f, ql1 = 0.0f;

    for (int c2 = 0; c2 < NCH; c2 += 2) {
        BWD_CHUNK(c2,     bufA, bufB)
        BWD_CHUNK(c2 + 1, bufB, bufA)
    }
}

// ---------------------------------------------------------------------------
extern "C" void kernel_launch(void* const* d_in, const int* in_sizes, int n_in,
                              void* d_out, int out_size, void* d_ws, size_t ws_size,
                              hipStream_t stream) {
    const float* zx = (const float*)d_in[0];
    const float* zy = (const float*)d_in[1];
    const float* gx = (const float*)d_in[2];
    const float* gy = (const float*)d_in[3];

    float* aln   = (float*)d_out;               // output 0: [B,N,M]
    float* theta = aln + B * NM;                // output 1
    float* Amat  = theta + B * NM;              // output 2

    float2* TAD = (float2*)d_ws;                // {theta,A} diag-interleaved, 16 MB
    float2* pD  = TAD + B * NM;                 // {p_up,p_lf} diag-interleaved, 16 MB
    float*  ED  = (float*)d_ws;                 // overlays TAD (dead after forward)

    gemm_act_kernel<<<dim3(8, 8, B * 2), dim3(16, 16), 0, stream>>>(zx, zy, gx, gy, theta, Amat);
    reorder_in_kernel<<<dim3(8, 8, B), 256, 0, stream>>>(theta, Amat, TAD);
    nw_forward_kernel<<<B, 512, 0, stream>>>(TAD, pD);
    nw_backward_kernel<<<B, 512, 0, stream>>>(pD, ED);
    reorder_out_kernel<<<dim3(8, 8, B), 256, 0, stream>>>(ED, aln);
}

// Round 10
// 773.923 us; speedup vs baseline: 1.2005x; 1.0175x over previous
//
#include <hip/hip_runtime.h>
#include <cmath>

#define NEG -1e9f
constexpr int B = 8, N = 512, M = 512, D = 512;
constexpr size_t NM = (size_t)N * M;   // 262144

constexpr int CH = 8;           // chunk = barrier interval = wave skew
constexpr int NCH = 136;        // even; covers makespan 1023 + 7*8 + 1 = 1080 (135 chunks)
// Forward: wave w active chunks [9w, 9w+71]; backward: [63-9w, 134-9w], K0=1078.

// DPP full-wave shifts (register-file; replaces ds_bpermute).
__device__ __forceinline__ float dpp_shr1(float v) {
    return __int_as_float(__builtin_amdgcn_update_dpp(
        __float_as_int(v), __float_as_int(v), 0x138, 0xf, 0xf, false));
}
__device__ __forceinline__ float dpp_shl1(float v) {
    return __int_as_float(__builtin_amdgcn_update_dpp(
        __float_as_int(v), __float_as_int(v), 0x130, 0xf, 0xf, false));
}

// Compact diagonal layout: cell (r,c) 0-based -> diag_off(kd) + r - max(0,kd-511)
__device__ __forceinline__ int diag_off(int kd) {
    return (kd <= 511) ? ((kd * (kd + 1)) >> 1)
                       : ((int)NM - (((1023 - kd) * (1024 - kd)) >> 1));
}
__device__ __forceinline__ int diag_flat_clamped(int kd, int r) {
    const int k = min(max(kd, 0), 1022);
    const int f = diag_off(k) + r - max(0, k - 511);
    return min(max(f, 0), (int)NM - 1);
}

// ---------------------------------------------------------------------------
// GEMM + activation: which=0 -> theta = softplus(zx . zy^T)
//                    which=1 -> A     = log_sigmoid(gx . gy^T)
// ---------------------------------------------------------------------------
__global__ __launch_bounds__(256)
void gemm_act_kernel(const float* __restrict__ zx, const float* __restrict__ zy,
                     const float* __restrict__ gx, const float* __restrict__ gy,
                     float* __restrict__ out_theta, float* __restrict__ out_A)
{
    const int bz = blockIdx.z;
    const int b = bz >> 1, which = bz & 1;
    const float* X = (which ? gx : zx) + (size_t)b * N * D;
    const float* Y = (which ? gy : zy) + (size_t)b * M * D;
    float* C = (which ? out_A : out_theta) + (size_t)b * NM;

    __shared__ float Xs[16][68];
    __shared__ float Ys[16][68];

    const int tx = threadIdx.x, ty = threadIdx.y;
    const int t = ty * 16 + tx;
    const int lrow = t >> 2;
    const int lk4 = (t & 3) * 4;
    const int row0 = blockIdx.y * 64, col0 = blockIdx.x * 64;

    float acc[4][4] = {};

    for (int k0 = 0; k0 < D; k0 += 16) {
        const float4 xv = *(const float4*)&X[(row0 + lrow) * D + k0 + lk4];
        const float4 yv = *(const float4*)&Y[(col0 + lrow) * D + k0 + lk4];
        Xs[lk4 + 0][lrow] = xv.x; Xs[lk4 + 1][lrow] = xv.y;
        Xs[lk4 + 2][lrow] = xv.z; Xs[lk4 + 3][lrow] = xv.w;
        Ys[lk4 + 0][lrow] = yv.x; Ys[lk4 + 1][lrow] = yv.y;
        Ys[lk4 + 2][lrow] = yv.z; Ys[lk4 + 3][lrow] = yv.w;
        __syncthreads();
#pragma unroll
        for (int kk = 0; kk < 16; kk++) {
            const float4 a = *(const float4*)&Xs[kk][ty * 4];
            const float4 bb = *(const float4*)&Ys[kk][tx * 4];
            acc[0][0] += a.x * bb.x; acc[0][1] += a.x * bb.y; acc[0][2] += a.x * bb.z; acc[0][3] += a.x * bb.w;
            acc[1][0] += a.y * bb.x; acc[1][1] += a.y * bb.y; acc[1][2] += a.y * bb.z; acc[1][3] += a.y * bb.w;
            acc[2][0] += a.z * bb.x; acc[2][1] += a.z * bb.y; acc[2][2] += a.z * bb.z; acc[2][3] += a.z * bb.w;
            acc[3][0] += a.w * bb.x; acc[3][1] += a.w * bb.y; acc[3][2] += a.w * bb.z; acc[3][3] += a.w * bb.w;
        }
        __syncthreads();
    }

#pragma unroll
    for (int r = 0; r < 4; r++) {
        float4 o;
        float* op = &o.x;
#pragma unroll
        for (int c = 0; c < 4; c++) {
            const float x = acc[r][c];
            const float l = log1pf(expf(-fabsf(x)));
            op[c] = which ? (fminf(x, 0.0f) - l)     // log_sigmoid
                          : (fmaxf(x, 0.0f) + l);   // softplus
        }
        *(float4*)&C[(size_t)(row0 + ty * 4 + r) * M + col0 + tx * 4] = o;
    }
}

// ---------------------------------------------------------------------------
// Row-major theta,A -> compact-diag interleaved float2 {theta, A}.
// ---------------------------------------------------------------------------
__global__ __launch_bounds__(256)
void reorder_in_kernel(const float* __restrict__ theta, const float* __restrict__ A,
                       float2* __restrict__ TAD)
{
    __shared__ float T[64][67];
    __shared__ float Ag[64][67];
    const int b = blockIdx.z;
    const float* ts = theta + (size_t)b * NM;
    const float* as = A + (size_t)b * NM;
    float2* dst = TAD + (size_t)b * NM;
    const int r0 = blockIdx.y * 64, c0 = blockIdx.x * 64;
    const int t = threadIdx.x, lane = t & 63, wv = t >> 6;

#pragma unroll
    for (int e = 0; e < 16; e++) {
        const int r = wv * 16 + e;
        T[r][lane]  = ts[(size_t)(r0 + r) * M + c0 + lane];
        Ag[r][lane] = as[(size_t)(r0 + r) * M + c0 + lane];
    }
    __syncthreads();
    for (int dd = wv; dd < 127; dd += 4) {
        const int kd = r0 + c0 + dd;
        const int rlo = max(0, dd - 63);
        const int L = min(63, dd) - rlo + 1;
        if (lane < L) {
            const int rloc = rlo + lane;
            const int gr = r0 + rloc;
            dst[diag_off(kd) + gr - max(0, kd - 511)] =
                make_float2(T[rloc][dd - rloc], Ag[rloc][dd - rloc]);
        }
    }
}

// ---------------------------------------------------------------------------
// Compact-diag E -> row-major aln.
// ---------------------------------------------------------------------------
__global__ __launch_bounds__(256)
void reorder_out_kernel(const float* __restrict__ ED, float* __restrict__ aln)
{
    __shared__ float T[64][67];
    const int b = blockIdx.z;
    const float* src = ED + (size_t)b * NM;
    float* dst = aln + (size_t)b * NM;
    const int r0 = blockIdx.y * 64, c0 = blockIdx.x * 64;
    const int t = threadIdx.x, lane = t & 63, wv = t >> 6;

    for (int dd = wv; dd < 127; dd += 4) {
        const int kd = r0 + c0 + dd;
        const int rlo = max(0, dd - 63);
        const int L = min(63, dd) - rlo + 1;
        if (lane < L) {
            const int rloc = rlo + lane;
            const int gr = r0 + rloc;
            T[rloc][dd - rloc] = src[diag_off(kd) + gr - max(0, kd - 511)];
        }
    }
    __syncthreads();
#pragma unroll
    for (int e = 0; e < 16; e++) {
        const int r = wv * 16 + e;
        dst[(size_t)(r0 + r) * M + c0 + lane] = T[r][lane];
    }
}

// ---------------------------------------------------------------------------
// Forward soft-NW: skew=8 pipeline, DPP shift, small (8-entry) register
// ping-pong double-buffer that cannot spill.
// ---------------------------------------------------------------------------
#define FWD_CHUNK(c_, CUR, NXT)                                                \
    {                                                                          \
        const int c = (c_);                                                    \
        /* unconditional clamped prefetch of chunk c+1 into NXT */             \
        {                                                                      \
            const int kb1 = 8 * (c + 1) - 8 * w;                               \
            _Pragma("unroll")                                                  \
            for (int s = 0; s < CH; s++)                                       \
                NXT[s] = tab[diag_flat_clamped(kb1 + s, tid)];                 \
        }                                                                      \
        if (c >= ca && c <= cb) {                                              \
            const int kb = 8 * c - 8 * w;                                      \
            float rg[CH];                                                      \
            _Pragma("unroll")                                                  \
            for (int s = 0; s < CH; s++)                                       \
                rg[s] = (w > 0) ? ring[w - 1][(kb + s - 1) & 63] : NEG;        \
            _Pragma("unroll")                                                  \
            for (int s = 0; s < CH; s++) {                                     \
                const int kd = kb + s;                                         \
                const int jj = kd - tid;                                       \
                float sh1 = dpp_shr1(vprev);                                   \
                if (lane == 0) sh1 = rg[s];                                    \
                const float dg = (jj == 0) ? ((tid == 0) ? 0.0f : NEG) : sh1_d;\
                sh1_d = sh1;                                                   \
                if (jj >= 0 && jj < M) {                                       \
                    const float th = CUR[s].x, a = CUR[s].y;                   \
                    const float x0 = a + sh1;                                  \
                    const float x2 = a + vprev;                                \
                    const float m = fmaxf(fmaxf(x0, dg), x2);                  \
                    const float e0 = __expf(x0 - m);                           \
                    const float e1 = __expf(dg - m);                           \
                    const float e2 = __expf(x2 - m);                           \
                    const float sum = e0 + e1 + e2;                            \
                    const float inv = __builtin_amdgcn_rcpf(sum);              \
                    const int f = diag_off(kd) + tid - max(0, kd - 511);       \
                    pb[f] = make_float2(e0 * inv, e2 * inv);                   \
                    vprev = th + m + __logf(sum);                              \
                    if (lane == 63) ring[w][kd & 63] = vprev;                  \
                }                                                              \
            }                                                                  \
        }                                                                      \
        __syncthreads();                                                       \
    }

__global__ __launch_bounds__(512)
void nw_forward_kernel(const float2* __restrict__ TAD, float2* __restrict__ pD)
{
    __shared__ float ring[8][64];
    const int b = blockIdx.x;
    const int tid = threadIdx.x;
    const int w = __builtin_amdgcn_readfirstlane(tid >> 6);
    const int lane = tid & 63;
    const float2* tab = TAD + (size_t)b * NM;
    float2* pb = pD + (size_t)b * NM;

    for (int x = tid; x < 8 * 64; x += 512) ((float*)ring)[x] = NEG;
    __syncthreads();

    const int ca = 9 * w, cb = 9 * w + 71;

    float2 bufA[CH], bufB[CH];
#pragma unroll
    for (int s = 0; s < CH; s++)                   // chunk 0 data (only w==0 reads it)
        bufA[s] = tab[diag_flat_clamped(s - 8 * w, tid)];

    float vprev = NEG, sh1_d = NEG;

    for (int c2 = 0; c2 < NCH; c2 += 2) {
        FWD_CHUNK(c2,     bufA, bufB)
        FWD_CHUNK(c2 + 1, bufB, bufA)
    }
}

// ---------------------------------------------------------------------------
// Backward adjoint, q-product form, skew=8 mirrored (wave 7 leads), DPP,
// small register ping-pong double-buffer. K0 = 1078 (wave 7 chunk 0 -> kd 1022).
// ---------------------------------------------------------------------------
#define BWD_CHUNK(c_, CUR, NXT)                                                \
    {                                                                          \
        const int c = (c_);                                                    \
        {                                                                      \
            const int kb1 = 1078 - 8 * (c + 1) - 8 * w;                        \
            _Pragma("unroll")                                                  \
            for (int s = 0; s < CH; s++)                                       \
                NXT[s] = pb[diag_flat_clamped(kb1 - s, tid)];                  \
        }                                                                      \
        if (c >= ca && c <= cb) {                                              \
            const int kb = 1078 - 8 * c - 8 * w;                               \
            float rgu[CH], rgd[CH];                                            \
            _Pragma("unroll")                                                  \
            for (int s = 0; s < CH; s++) {                                     \
                rgu[s] = (w < 7) ? ring_u[w + 1][(kb - s + 1) & 63] : 0.0f;    \
                rgd[s] = (w < 7) ? ring_d[w + 1][(kb - s + 2) & 63] : 0.0f;    \
            }                                                                  \
            _Pragma("unroll")                                                  \
            for (int s = 0; s < CH; s++) {                                     \
                const int kd = kb - s;                                         \
                const int jj = kd - tid;                                       \
                float su = dpp_shl1(qu1);                                      \
                float sd = dpp_shl1(qd2);                                      \
                if (lane == 63) { su = rgu[s]; sd = rgd[s]; }                  \
                if (jj >= 0 && jj < M) {                                       \
                    float e = su + sd + ql1;                                   \
                    if (tid == N - 1 && jj == M - 1) e = 1.0f;                 \
                    const float pu = CUR[s].x, pl = CUR[s].y;                  \
                    const float pd = 1.0f - pu - pl;                           \
                    const float qu = pu * e, qd = pd * e, ql = pl * e;         \
                    const int f = diag_off(kd) + tid - max(0, kd - 511);       \
                    eb[f] = e;                                                 \
                    qd2 = qd1; qd1 = qd; qu1 = qu; ql1 = ql;                   \
                    if (lane == 0) {                                           \
                        ring_u[w][kd & 63] = qu;                               \
                        ring_d[w][kd & 63] = qd;                               \
                    }                                                          \
                }                                                              \
            }                                                                  \
        }                                                                      \
        __syncthreads();                                                       \
    }

__global__ __launch_bounds__(512)
void nw_backward_kernel(const float2* __restrict__ pD, float* __restrict__ ED)
{
    __shared__ float ring_u[8][64];
    __shared__ float ring_d[8][64];
    const int b = blockIdx.x;
    const int tid = threadIdx.x;
    const int w = __builtin_amdgcn_readfirstlane(tid >> 6);
    const int lane = tid & 63;
    const float2* pb = pD + (size_t)b * NM;
    float* eb = ED + (size_t)b * NM;

    for (int x = tid; x < 8 * 64; x += 512) {
        ((float*)ring_u)[x] = 0.0f;
        ((float*)ring_d)[x] = 0.0f;
    }
    __syncthreads();

    const int ca = 63 - 9 * w, cb = 134 - 9 * w;

    float2 bufA[CH], bufB[CH];
#pragma unroll
    for (int s = 0; s < CH; s++)                   // chunk-0 data: kb(0)=1078-8w
        bufA[s] = pb[diag_flat_clamped(1078 - 8 * w - s, tid)];   // w=7 -> 1022-s

    float qu1 = 0.0f, qd1 = 0.0f, qd2 = 0.0f, ql1 = 0.0f;

    for (int c2 = 0; c2 < NCH; c2 += 2) {
        BWD_CHUNK(c2,     bufA, bufB)
        BWD_CHUNK(c2 + 1, bufB, bufA)
    }
}

// ---------------------------------------------------------------------------
extern "C" void kernel_launch(void* const* d_in, const int* in_sizes, int n_in,
                              void* d_out, int out_size, void* d_ws, size_t ws_size,
                              hipStream_t stream) {
    const float* zx = (const float*)d_in[0];
    const float* zy = (const float*)d_in[1];
    const float* gx = (const float*)d_in[2];
    const float* gy = (const float*)d_in[3];

    float* aln   = (float*)d_out;               // output 0: [B,N,M]
    float* theta = aln + B * NM;                // output 1
    float* Amat  = theta + B * NM;              // output 2

    float2* TAD = (float2*)d_ws;                // {theta,A} diag-interleaved, 16 MB
    float2* pD  = TAD + B * NM;                 // {p_up,p_lf} diag-interleaved, 16 MB
    float*  ED  = (float*)d_ws;                 // overlays TAD (dead after forward)

    gemm_act_kernel<<<dim3(8, 8, B * 2), dim3(16, 16), 0, stream>>>(zx, zy, gx, gy, theta, Amat);
    reorder_in_kernel<<<dim3(8, 8, B), 256, 0, stream>>>(theta, Amat, TAD);
    nw_forward_kernel<<<B, 512, 0, stream>>>(TAD, pD);
    nw_backward_kernel<<<B, 512, 0, stream>>>(pD, ED);
    reorder_out_kernel<<<dim3(8, 8, B), 256, 0, stream>>>(ED, aln);
}